// Round 9
// baseline (690.555 us; speedup 1.0000x reference)
//
#include <hip/hip_runtime.h>

// ---------------------------------------------------------------------------
// EdgeLLMAttentionTRTNative: out = X @ (s*Wo@Wq)^T + kv_cache passthrough.
// Round 9: round 8 + the NaN fix. global_load_lds writes LDS at
// wave-uniform-base + lane*16, so the STAGE dest MUST include the per-wave
// offset (w*1024); round 8 dropped it and all 4 waves aliased one 1KB slice.
// Structure: BM=128 BN=256, 4 waves, per-wave 128x64, BK=32, 2-slot LDS
// (48KB) -> 3 blocks/CU; one barrier + vmcnt(0)/tile (drain hidden by the
// other 2 co-resident blocks). Grids: big 768 = 3/CU exactly; small 288.
// ---------------------------------------------------------------------------

typedef __attribute__((ext_vector_type(8))) __bf16 bf16x8;
typedef __attribute__((ext_vector_type(4))) float f32x4;

__device__ __forceinline__ unsigned short f2bf(float f) {
  union { float f; unsigned u; } v; v.f = f;
  unsigned r = v.u + 0x7fffu + ((v.u >> 16) & 1u);   // round-to-nearest-even
  return (unsigned short)(r >> 16);
}

__global__ void cast_f32_to_bf16(const float4* __restrict__ in,
                                 ushort4* __restrict__ out, int n4) {
  int i = blockIdx.x * blockDim.x + threadIdx.x;
  int stride = gridDim.x * blockDim.x;
  for (; i < n4; i += stride) {
    float4 v = in[i];
    ushort4 o;
    o.x = f2bf(v.x); o.y = f2bf(v.y); o.z = f2bf(v.z); o.w = f2bf(v.w);
    out[i] = o;
  }
}

// out (C x R, bf16) = transpose of in (R x C, fp32)
__global__ void transpose_cast(const float* __restrict__ in,
                               ushort* __restrict__ out, int R, int C) {
  __shared__ float tile[32][33];
  const int tc = blockIdx.x * 32;
  const int tr = blockIdx.y * 32;
  const int lx = threadIdx.x & 31;
  const int ly = threadIdx.x >> 5;
#pragma unroll
  for (int i = 0; i < 32; i += 8)
    tile[ly + i][lx] = in[(size_t)(tr + ly + i) * C + (tc + lx)];
  __syncthreads();
#pragma unroll
  for (int i = 0; i < 32; i += 8)
    out[(size_t)(tc + ly + i) * R + (tr + lx)] = f2bf(tile[lx][ly + i]);
}

typedef const __attribute__((address_space(1))) void* gptr_t;
typedef __attribute__((address_space(3))) void* lptr_t;

__device__ __forceinline__ void gload16(const void* g, void* l) {
  __builtin_amdgcn_global_load_lds((gptr_t)g, (lptr_t)l, 16, 0, 0);
}

#define BAR   do { asm volatile("" ::: "memory"); __builtin_amdgcn_s_barrier(); asm volatile("" ::: "memory"); } while (0)
#define LGKM0 asm volatile("s_waitcnt lgkmcnt(0)" ::: "memory")
#define VM(n) asm volatile("s_waitcnt vmcnt(" #n ")" ::: "memory")

// ---------------------------------------------------------------------------
// GEMM: C = A(MxK) * B(NxK)^T, bf16 in, f32 or scaled-bf16 out.
// BM=128 BN=256 BK=32; 4 waves 1Mx4N, per-wave 128x64, acc[8][4].
// LDS slot: A 128x32 (8KB) + B 256x32 (16KB) = 24KB; x2 slots = 48KB.
// Swizzle: 16B chunk c of row r stored at c^((r>>1)&3) via pre-swizzled
// global source + XOR'd read offset (rounds 3/7: SQ_LDS_BANK_CONFLICT = 0).
// Staging geometry (per 4KB region, 6 regions/tile): wave w covers rows
// [w*16, w*16+16) of the region; LDS dest = region + w*1024 (wave-uniform)
// + lane*16 (HW). Thread t=(w*64+lane): dest row = t>>2 == source row. The
// round-8 bug was omitting the w*1024 term.
// Tile T (slot s=T&1): stage T+1 -> s^1 (T-1's reads of s^1 drained before
// its end barrier); vmcnt(0)+BAR at tile end. One barrier per tile; the
// drain is hidden by the 2 other co-resident blocks.
// ---------------------------------------------------------------------------
template <int OUT_BF16>
__global__ __launch_bounds__(256, 3)
void gemm_d(const ushort* __restrict__ A, const ushort* __restrict__ B,
            void* __restrict__ Cv, int M, int N, int K, float scale) {
  __shared__ __align__(16) char smem[49152];

  const int t    = threadIdx.x;        // 0..255
  const int lane = t & 63;
  const int wc   = t >> 6;             // 0..3 (N: 64 cols each)
  const int fr   = lane & 15;
  const int g    = lane >> 4;          // 0..3
  const int wofs = (t >> 6) << 10;     // per-wave dest offset (the fix)

  // XCD-aware bijective swizzle: nwg % 8 == 0 by construction.
  const int nwg = gridDim.x;
  const int cpx = nwg >> 3;
  const int wg  = (blockIdx.x & 7) * cpx + (blockIdx.x >> 3);
  const int nbx = N >> 8;
  const int bx  = wg % nbx, by = wg / nbx;
  const int rowBase = by * 128, colBase = bx * 256;

  // Staging source: thread t -> row t>>2 (0..63), stored chunk t&3 holds
  // logical chunk (t&3)^((t>>3)&3) (since (row>>1)&3 == (t>>3)&3).
  const int srow = t >> 2;                              // 0..63
  const int scol = ((t & 3) ^ ((t >> 3) & 3)) << 3;     // pre-swizzled col
  const ushort* Ag = A + (size_t)(rowBase + srow) * K + scol;
  const ushort* Bg = B + (size_t)(colBase + srow) * K + scol;

#define SLOT(T) (((T) & 1) * 24576)
// A: 128 rows = 2 regions; B: 256 rows = 4 regions. 6 vm-ops/tile/wave.
#define STAGE(kt) do {                                                  \
    char* d_ = smem + SLOT(kt) + wofs;                                  \
    const ushort* sa_ = Ag + (size_t)(kt) * 32;                         \
    gload16(sa_, d_);                                                   \
    gload16(sa_ + (size_t)64 * K, d_ + 4096);                           \
    const ushort* sb_ = Bg + (size_t)(kt) * 32;                         \
    gload16(sb_,                    d_ + 8192);                         \
    gload16(sb_ + (size_t)64 * K,   d_ + 12288);                        \
    gload16(sb_ + (size_t)128 * K,  d_ + 16384);                        \
    gload16(sb_ + (size_t)192 * K,  d_ + 20480); } while (0)

  // Fragment reads: row stride 64B; logical chunk g stored at g^((fr>>1)&3).
  const int cs   = (g ^ ((fr >> 1) & 3)) << 4;
  const int aOff = fr * 64 + cs;                        // + MH*4096 + m*1024
  const int bOff = 8192 + (wc * 64 + fr) * 64 + cs;     // + n*1024

#define READ_A(dst, so, MH) do {                                        \
    const char* p_ = smem + (so) + aOff + (MH) * 4096;                  \
    dst[0] = *(const bf16x8*)(p_);                                      \
    dst[1] = *(const bf16x8*)(p_ + 1024);                               \
    dst[2] = *(const bf16x8*)(p_ + 2048);                               \
    dst[3] = *(const bf16x8*)(p_ + 3072); } while (0)
#define READ_B(dst, so) do {                                            \
    const char* p_ = smem + (so) + bOff;                                \
    dst[0] = *(const bf16x8*)(p_);                                      \
    dst[1] = *(const bf16x8*)(p_ + 1024);                               \
    dst[2] = *(const bf16x8*)(p_ + 2048);                               \
    dst[3] = *(const bf16x8*)(p_ + 3072); } while (0)
#define MFMA16(MH, A4, B4) do {                                         \
    _Pragma("unroll") for (int mi_ = 0; mi_ < 4; ++mi_)                 \
    _Pragma("unroll") for (int ni_ = 0; ni_ < 4; ++ni_)                 \
      acc[(MH) * 4 + mi_][ni_] = __builtin_amdgcn_mfma_f32_16x16x32_bf16( \
          A4[mi_], B4[ni_], acc[(MH) * 4 + mi_][ni_], 0, 0, 0); } while (0)

  f32x4 acc[8][4];
#pragma unroll
  for (int m = 0; m < 8; ++m)
#pragma unroll
    for (int n = 0; n < 4; ++n)
      acc[m][n] = f32x4{0.f, 0.f, 0.f, 0.f};

  bf16x8 Af[4], Bf[4];

  const int nt = K >> 5;               // 96

  // Prologue: stage tile 0, drain, barrier.
  STAGE(0);
  VM(0);
  BAR;

  for (int T = 0; T < nt; ++T) {
    const int so = SLOT(T);
    READ_A(Af, so, 0);
    READ_B(Bf, so);
    if (T + 1 < nt) STAGE(T + 1);      // -> slot so^1; safe: T-1's reads of
                                       // so^1 drained before its barrier
    LGKM0;
    __builtin_amdgcn_s_setprio(1); MFMA16(0, Af, Bf); __builtin_amdgcn_s_setprio(0);
    READ_A(Af, so, 1);
    LGKM0;
    __builtin_amdgcn_s_setprio(1); MFMA16(1, Af, Bf); __builtin_amdgcn_s_setprio(0);
    VM(0);                             // tile T+1 fully in LDS
    BAR;                               // all waves' reads of slot so done
  }

#undef STAGE
#undef READ_A
#undef READ_B
#undef MFMA16
#undef SLOT

  // C/D layout: col = lane&15, row = (lane>>4)*4 + i
  const int ocol = colBase + wc * 64 + fr;
#pragma unroll
  for (int mi = 0; mi < 8; ++mi) {
    const int orow = rowBase + (mi >> 2) * 64 + (mi & 3) * 16 + (g << 2);
#pragma unroll
    for (int ni = 0; ni < 4; ++ni)
#pragma unroll
      for (int i = 0; i < 4; ++i) {
        const size_t idx = (size_t)(orow + i) * N + (ocol + ni * 16);
        float v = acc[mi][ni][i] * scale;
        if (OUT_BF16) ((ushort*)Cv)[idx] = f2bf(v);
        else          ((float*)Cv)[idx]  = v;
      }
  }
}

extern "C" void kernel_launch(void* const* d_in, const int* in_sizes, int n_in,
                              void* d_out, int out_size, void* d_ws, size_t ws_size,
                              hipStream_t stream) {
  const float* hs = (const float*)d_in[0];   // (4,2048,3072)
  const float* kv = (const float*)d_in[4];   // (4,2,8,4096,128)
  const float* Wq = (const float*)d_in[5];   // (3072,3072) (d,h)
  const float* Wo = (const float*)d_in[8];   // (3072,3072) (o,d)

  const int M = 8192, H = 3072;
  const int OUT_ELEMS = M * H;

  float* out = (float*)d_out;

  ushort* Xb   = (ushort*)d_ws;
  ushort* Wob  = Xb + (size_t)M * H;
  ushort* WqTb = Wob + (size_t)H * H;
  // Fused weight W = s*Wo@Wq (bf16) in the kv-tail of d_out; overwritten by
  // the kv_cache copy afterwards (stream-ordered).
  ushort* Wb   = (ushort*)(out + OUT_ELEMS);

  cast_f32_to_bf16<<<2048, 256, 0, stream>>>((const float4*)hs, (ushort4*)Xb, (M * H) / 4);
  cast_f32_to_bf16<<<1024, 256, 0, stream>>>((const float4*)Wo, (ushort4*)Wob, (H * H) / 4);
  transpose_cast<<<dim3(H / 32, H / 32), 256, 0, stream>>>(Wq, WqTb, H, H);

  const float qk_scale = 0.08838834764831845f;  // 128^-0.5
  // W[o,h] = s * sum_d Wo[o,d] * Wq[d,h]   (grid 24*12 = 288, %8==0)
  gemm_d<1><<<(H / 128) * (H / 256), 256, 0, stream>>>(Wob, WqTb, (void*)Wb, H, H, H, qk_scale);
  // out[m,o] = sum_h X[m,h] * W[o,h]       (grid 64*12 = 768 = 3/CU x 256)
  gemm_d<0><<<(M / 128) * (H / 256), 256, 0, stream>>>(Xb, Wb, (void*)out, M, H, H, 1.0f);

  hipMemcpyAsync(out + OUT_ELEMS, kv, (size_t)in_sizes[4] * sizeof(float),
                 hipMemcpyDeviceToDevice, stream);
}

// Round 10
// 418.648 us; speedup vs baseline: 1.6495x; 1.6495x over previous
//
#include <hip/hip_runtime.h>

// ---------------------------------------------------------------------------
// EdgeLLMAttentionTRTNative: out = X @ (s*Wo@Wq)^T + kv_cache passthrough.
// Round 10: round-7 inner loop (proven: 4-slot ring, vmcnt(2), 16 MFMA/phase,
// chunk-XOR swizzle, 0 bank conflicts) with EXACT grid fill via N-split:
//   K1: BN=256, cols 0..2047,  grid 32x8 = 256 = exactly 1 round @ 1 blk/CU
//   K2: BN=128, cols 2048..3071, grid 256 = exactly 1 round (half duration)
// Column-major block->XCD map (1 B-panel resident per XCD). kv_cache copy
// fused into K1/K2 epilogues (rides under compute); Wb moved to d_ws when
// ws_size permits (runtime guard, else fallback to memcpy path).
// ---------------------------------------------------------------------------

typedef __attribute__((ext_vector_type(8))) __bf16 bf16x8;
typedef __attribute__((ext_vector_type(4))) float f32x4;

__device__ __forceinline__ unsigned short f2bf(float f) {
  union { float f; unsigned u; } v; v.f = f;
  unsigned r = v.u + 0x7fffu + ((v.u >> 16) & 1u);   // round-to-nearest-even
  return (unsigned short)(r >> 16);
}

__global__ void cast_f32_to_bf16(const float4* __restrict__ in,
                                 ushort4* __restrict__ out, int n4) {
  int i = blockIdx.x * blockDim.x + threadIdx.x;
  int stride = gridDim.x * blockDim.x;
  for (; i < n4; i += stride) {
    float4 v = in[i];
    ushort4 o;
    o.x = f2bf(v.x); o.y = f2bf(v.y); o.z = f2bf(v.z); o.w = f2bf(v.w);
    out[i] = o;
  }
}

// out (C x R, bf16) = transpose of in (R x C, fp32)
__global__ void transpose_cast(const float* __restrict__ in,
                               ushort* __restrict__ out, int R, int C) {
  __shared__ float tile[32][33];
  const int tc = blockIdx.x * 32;
  const int tr = blockIdx.y * 32;
  const int lx = threadIdx.x & 31;
  const int ly = threadIdx.x >> 5;
#pragma unroll
  for (int i = 0; i < 32; i += 8)
    tile[ly + i][lx] = in[(size_t)(tr + ly + i) * C + (tc + lx)];
  __syncthreads();
#pragma unroll
  for (int i = 0; i < 32; i += 8)
    out[(size_t)(tc + ly + i) * R + (tr + lx)] = f2bf(tile[lx][ly + i]);
}

typedef const __attribute__((address_space(1))) void* gptr_t;
typedef __attribute__((address_space(3))) void* lptr_t;

__device__ __forceinline__ void gload16(const void* g, void* l) {
  __builtin_amdgcn_global_load_lds((gptr_t)g, (lptr_t)l, 16, 0, 0);
}

#define BAR   do { asm volatile("" ::: "memory"); __builtin_amdgcn_s_barrier(); asm volatile("" ::: "memory"); } while (0)
#define LGKM0 asm volatile("s_waitcnt lgkmcnt(0)" ::: "memory")
#define VM(n) asm volatile("s_waitcnt vmcnt(" #n ")" ::: "memory")

// ---------------------------------------------------------------------------
// GEMM: C = A(Mx K) * B(rows x K)^T, bf16 in; f32 or scaled-bf16 out.
// BM=256 fixed; BN in {128,256}. BK=32. 8 waves 2Mx4N, per-wave 128x(BN/4).
// LDS: 4 slots x (A 16KB + B BN*64B) = 96KB (BN=128) / 128KB (BN=256).
// Swizzle: 16B chunk c of row r stored at c^((r>>1)&3), pre-swizzled global
// source + XOR'd read (rounds 3/7: 0 conflicts).
// Schedule per tile T (slots T, T+1, T+2 distinct mod 4):
//  Ph1: read Af1(slot T); stage A(T+2); BAR; LGKM0; 4xNB MFMA (Af0 x Bcur);
//       VM(2|0); BAR.   [VM(2): only A(T+2) in flight => T+1 fully landed]
//  Ph2: read Af0/Bnext(slot T+1); stage B(T+2); BAR; LGKM0; 4xNB MFMA
//       (Af1 x Bcur); BAR.
// Optional fused kv-copy epilogue (kvdst != nullptr).
// ---------------------------------------------------------------------------
template <int BN, int OUT_BF16>
__global__ __launch_bounds__(512, 2)
void gemm_t(const ushort* __restrict__ A, const ushort* __restrict__ B,
            void* __restrict__ Cv, int nby, int K, int ldc, int cofs,
            float scale,
            const float4* __restrict__ kvsrc, float4* __restrict__ kvdst,
            int kvblk0, int nkv4) {
  constexpr int NB      = BN / 64;            // B frags per k-step
  constexpr int SLOT_ST = 16384 + BN * 64;    // A 16KB + B BN*64B
  __shared__ __align__(16) char smem[4 * SLOT_ST];

  const int t    = threadIdx.x;
  const int w    = t >> 6;
  const int lane = t & 63;
  const int wr   = w >> 2;             // 0..1  (M: 128 rows each)
  const int wc   = w & 3;              // 0..3  (N: BN/4 cols each)
  const int fr   = lane & 15;
  const int g    = lane >> 4;          // 0..3

  // XCD-aware bijective swizzle; column-major tile map (B-panel per XCD).
  const int nwg = gridDim.x;
  const int cpx = nwg >> 3;
  const int wg  = (blockIdx.x & 7) * cpx + (blockIdx.x >> 3);
  const int by  = wg % nby, bx = wg / nby;
  const int rowBase = by * 256;
  const int bcol    = bx * BN;         // B-row base
  const int ccol    = cofs + bcol;     // C-col base

  // Staging source: thread t -> row t>>2 (0..127), stored chunk t&3 holds
  // logical chunk (t&3)^((t>>3)&3) (since (row>>1)&3 == (t>>3)&3).
  const int srow = t >> 2;
  const int scol = ((t & 3) ^ ((t >> 3) & 3)) << 3;
  const ushort* Ag = A + (size_t)(rowBase + srow) * K + scol;
  const ushort* Bg = B + (size_t)(bcol + srow) * K + scol;
  const int wofs = w << 10;            // per-wave LDS dest offset

#define SLOT(T) (((T) & 3) * SLOT_ST)
#define STAGE_A(kt) do { char* d_ = smem + SLOT(kt) + wofs;             \
    const ushort* s_ = Ag + (size_t)(kt) * 32;                          \
    gload16(s_, d_); gload16(s_ + (size_t)128 * K, d_ + 8192); } while (0)
#define STAGE_B(kt) do { char* d_ = smem + SLOT(kt) + 16384 + wofs;     \
    const ushort* s_ = Bg + (size_t)(kt) * 32;                          \
    gload16(s_, d_);                                                    \
    if (BN == 256) gload16(s_ + (size_t)128 * K, d_ + 8192); } while (0)

  // Fragment reads: row stride 64B; logical chunk g stored at g^((fr>>1)&3).
  const int cs   = (g ^ ((fr >> 1) & 3)) << 4;
  const int aOff = (wr * 128 + fr) * 64 + cs;             // + MH*4096 + m*1024
  const int bOff = 16384 + (wc * (BN / 4) + fr) * 64 + cs; // + n*1024

#define READ_A(dst, so, MH) do {                                        \
    const char* p_ = smem + (so) + aOff + (MH) * 4096;                  \
    _Pragma("unroll") for (int i_ = 0; i_ < 4; ++i_)                    \
      dst[i_] = *(const bf16x8*)(p_ + i_ * 1024); } while (0)
#define READ_B(dst, so) do {                                            \
    const char* p_ = smem + (so) + bOff;                                \
    _Pragma("unroll") for (int i_ = 0; i_ < NB; ++i_)                   \
      dst[i_] = *(const bf16x8*)(p_ + i_ * 1024); } while (0)
#define MFMAQ(MH, A4, B4) do {                                          \
    _Pragma("unroll") for (int mi_ = 0; mi_ < 4; ++mi_)                 \
    _Pragma("unroll") for (int ni_ = 0; ni_ < NB; ++ni_)                \
      acc[(MH) * 4 + mi_][ni_] = __builtin_amdgcn_mfma_f32_16x16x32_bf16( \
          A4[mi_], B4[ni_], acc[(MH) * 4 + mi_][ni_], 0, 0, 0); } while (0)

  f32x4 acc[8][NB];
#pragma unroll
  for (int m = 0; m < 8; ++m)
#pragma unroll
    for (int n = 0; n < NB; ++n)
      acc[m][n] = f32x4{0.f, 0.f, 0.f, 0.f};

  bf16x8 Af0[4], Af1[4], Bp[NB], Bq[NB];

  const int nt = K >> 5;               // 96 (even)

  // Prologue: stage tiles 0,1; wait tile 0 landed; pre-read Af0/Bp(tile 0).
  STAGE_A(0); STAGE_B(0);
  STAGE_A(1); STAGE_B(1);
  if (BN == 256) { VM(4); } else { VM(3); }
  BAR;
  READ_A(Af0, SLOT(0), 0);
  READ_B(Bp, SLOT(0));

#define TILE_BODY(T, BC, BN_) do {                                            \
    const int so_  = SLOT(T);                                                 \
    const int so1_ = SLOT((T) + 1);                                           \
    const bool stg_ = (T) + 2 < nt;                                           \
    /* Ph1 */                                                                 \
    READ_A(Af1, so_, 1);                                                      \
    if (stg_) STAGE_A((T) + 2);                                               \
    BAR; LGKM0;                                                               \
    __builtin_amdgcn_s_setprio(1); MFMAQ(0, Af0, BC); __builtin_amdgcn_s_setprio(0); \
    if ((T) < nt - 2) { VM(2); } else { VM(0); }                              \
    BAR;                                                                      \
    /* Ph2 */                                                                 \
    if ((T) + 1 < nt) { READ_A(Af0, so1_, 0); READ_B(BN_, so1_); }            \
    if (stg_) STAGE_B((T) + 2);                                               \
    BAR; LGKM0;                                                               \
    __builtin_amdgcn_s_setprio(1); MFMAQ(1, Af1, BC); __builtin_amdgcn_s_setprio(0); \
    BAR;                                                                      \
  } while (0)

  for (int T = 0; T < nt; T += 2) {
    TILE_BODY(T, Bp, Bq);
    TILE_BODY(T + 1, Bq, Bp);
  }

#undef TILE_BODY
#undef STAGE_A
#undef STAGE_B
#undef READ_A
#undef READ_B
#undef MFMAQ
#undef SLOT

  // C/D layout: col = lane&15, row = (lane>>4)*4 + i
  const int orow = rowBase + wr * 128 + (g << 2);
  const int ocol = ccol + wc * (BN / 4) + fr;
#pragma unroll
  for (int mi = 0; mi < 8; ++mi)
#pragma unroll
    for (int ni = 0; ni < NB; ++ni)
#pragma unroll
      for (int i = 0; i < 4; ++i) {
        const size_t idx = (size_t)(orow + mi * 16 + i) * ldc + (ocol + ni * 16);
        float v = acc[mi][ni][i] * scale;
        if (OUT_BF16) ((ushort*)Cv)[idx] = f2bf(v);
        else          ((float*)Cv)[idx]  = v;
      }

  // Fused kv_cache passthrough (independent of GEMM; rides under compute
  // of other blocks). Each block copies one chunk of float4s.
  if (kvdst) {
    const int gbi = kvblk0 + blockIdx.x;        // 0..511 across K1+K2
    const int chunk = nkv4 >> 9;                // nkv4 / 512
    size_t beg = (size_t)gbi * chunk + t;
    size_t end = (gbi == 511) ? (size_t)nkv4 : (size_t)(gbi + 1) * chunk;
    for (size_t i = beg; i < end; i += 512)
      kvdst[i] = kvsrc[i];
  }
}

extern "C" void kernel_launch(void* const* d_in, const int* in_sizes, int n_in,
                              void* d_out, int out_size, void* d_ws, size_t ws_size,
                              hipStream_t stream) {
  const float* hs = (const float*)d_in[0];   // (4,2048,3072)
  const float* kv = (const float*)d_in[4];   // (4,2,8,4096,128)
  const float* Wq = (const float*)d_in[5];   // (3072,3072) (d,h)
  const float* Wo = (const float*)d_in[8];   // (3072,3072) (o,d)

  const int M = 8192, H = 3072;
  const int OUT_ELEMS = M * H;
  const int nkv  = in_sizes[4];              // 33_554_432 floats
  const int nkv4 = nkv / 4;

  float* out = (float*)d_out;

  // Workspace layout (bf16): Xb 48MB, Wob 18MB, WqTb 18MB, [Wb 18MB].
  ushort* Xb   = (ushort*)d_ws;
  ushort* Wob  = Xb + (size_t)M * H;
  ushort* WqTb = Wob + (size_t)H * H;
  const size_t WS_NEED = 2ull * ((size_t)M * H + 3ull * (size_t)H * H);
  const bool ws_ok = ws_size >= WS_NEED;
  // Wb in ws when possible (enables fused kv copy); else in d_out kv-tail
  // (overwritten by the trailing memcpy, stream-ordered).
  ushort* Wb = ws_ok ? (WqTb + (size_t)H * H) : (ushort*)(out + OUT_ELEMS);

  cast_f32_to_bf16<<<2048, 256, 0, stream>>>((const float4*)hs, (ushort4*)Xb, (M * H) / 4);
  cast_f32_to_bf16<<<1024, 256, 0, stream>>>((const float4*)Wo, (ushort4*)Wob, (H * H) / 4);
  transpose_cast<<<dim3(H / 32, H / 32), 256, 0, stream>>>(Wq, WqTb, H, H);

  const float qk_scale = 0.08838834764831845f;  // 128^-0.5

  // Small GEMM: W[o,h] = s * sum_d Wo[o,d]*Wq[d,h]. BM=256 BN=128,
  // grid = (3072/256) x (3072/128) = 12*24 = 288 (%8==0).
  gemm_t<128, 1><<<288, 512, 0, stream>>>(
      Wob, WqTb, (void*)Wb, /*nby=*/H / 256, /*K=*/H, /*ldc=*/H, /*cofs=*/0,
      qk_scale, nullptr, nullptr, 0, 0);

  const float4* kvs = ws_ok ? (const float4*)kv : nullptr;
  float4* kvd = ws_ok ? (float4*)(out + OUT_ELEMS) : nullptr;

  // Big GEMM, N-split for exact grid fill (each = 256 blocks = 1 round):
  // K1: cols [0,2048) BN=256; K2: cols [2048,3072) BN=128.
  gemm_t<256, 0><<<256, 512, 0, stream>>>(
      Xb, Wb, (void*)out, /*nby=*/M / 256, /*K=*/H, /*ldc=*/H, /*cofs=*/0,
      1.0f, kvs, kvd, /*kvblk0=*/0, nkv4);
  gemm_t<128, 0><<<256, 512, 0, stream>>>(
      Xb, Wb + (size_t)2048 * H, (void*)out, /*nby=*/M / 256, /*K=*/H,
      /*ldc=*/H, /*cofs=*/2048, 1.0f, kvs, kvd, /*kvblk0=*/256, nkv4);

  if (!ws_ok) {
    // Fallback: Wb lived in the kv-tail; overwrite it with the real kv now.
    hipMemcpyAsync(out + OUT_ELEMS, kv, (size_t)nkv * sizeof(float),
                   hipMemcpyDeviceToDevice, stream);
  }
}

// Round 11
// 333.735 us; speedup vs baseline: 2.0692x; 1.2544x over previous
//
#include <hip/hip_runtime.h>

// ---------------------------------------------------------------------------
// EdgeLLMAttentionTRTNative: out = X @ (s*Wo@Wq)^T + kv_cache passthrough.
// Round 11: consolidation. Big GEMM = round-5's verified best (BM=256 BN=192
// BK=64, 8 waves 2Mx4N, 2-buffer LDS 112KB, 4 phases/tile, vmcnt(3) ladder,
// chunk-XOR swizzle; 167us/925TF measured). Small GEMM runs the SAME kernel
// (grid 192). kv_cache copy fused into the big GEMM epilogue (512 blocks x
// 16384 float4 exactly; hidden under round-2 compute). No trailing memcpy
// unless ws doesn't fit Wb (fallback path).
// ---------------------------------------------------------------------------

typedef __attribute__((ext_vector_type(8))) __bf16 bf16x8;
typedef __attribute__((ext_vector_type(4))) float f32x4;

__device__ __forceinline__ unsigned short f2bf(float f) {
  union { float f; unsigned u; } v; v.f = f;
  unsigned r = v.u + 0x7fffu + ((v.u >> 16) & 1u);   // round-to-nearest-even
  return (unsigned short)(r >> 16);
}

__global__ void cast_f32_to_bf16(const float4* __restrict__ in,
                                 ushort4* __restrict__ out, int n4) {
  int i = blockIdx.x * blockDim.x + threadIdx.x;
  int stride = gridDim.x * blockDim.x;
  for (; i < n4; i += stride) {
    float4 v = in[i];
    ushort4 o;
    o.x = f2bf(v.x); o.y = f2bf(v.y); o.z = f2bf(v.z); o.w = f2bf(v.w);
    out[i] = o;
  }
}

// out (C x R, bf16) = transpose of in (R x C, fp32)
__global__ void transpose_cast(const float* __restrict__ in,
                               ushort* __restrict__ out, int R, int C) {
  __shared__ float tile[32][33];
  const int tc = blockIdx.x * 32;
  const int tr = blockIdx.y * 32;
  const int lx = threadIdx.x & 31;
  const int ly = threadIdx.x >> 5;
#pragma unroll
  for (int i = 0; i < 32; i += 8)
    tile[ly + i][lx] = in[(size_t)(tr + ly + i) * C + (tc + lx)];
  __syncthreads();
#pragma unroll
  for (int i = 0; i < 32; i += 8)
    out[(size_t)(tc + ly + i) * R + (tr + lx)] = f2bf(tile[lx][ly + i]);
}

typedef const __attribute__((address_space(1))) void* gptr_t;
typedef __attribute__((address_space(3))) void* lptr_t;

__device__ __forceinline__ void gload16(const void* g, void* l) {
  __builtin_amdgcn_global_load_lds((gptr_t)g, (lptr_t)l, 16, 0, 0);
}

#define BAR   do { asm volatile("" ::: "memory"); __builtin_amdgcn_s_barrier(); asm volatile("" ::: "memory"); } while (0)
#define LGKM0 asm volatile("s_waitcnt lgkmcnt(0)" ::: "memory")
#define VM(n) asm volatile("s_waitcnt vmcnt(" #n ")" ::: "memory")

// ---------------------------------------------------------------------------
// GEMM (round-5 verified): C = A(MxK) * B(NxK)^T, bf16 in. BM=256 BN=192
// BK=64. 8 waves 2Mx4N; per-wave 128x48 out -> acc[8][3].
// LDS buffer: A[256][64] (32KB) + B[192][64] (24KB); 2 buffers = 112KB.
// Swizzle: 16B chunk c of row r stored at c^(r&7) (pre-swizzled global src).
// Region lifetimes within tile T (buffer bo = T&1; T+2 also targets bo):
//   B read kh0@P4(prev), kh1@P1  -> free P2+   -> stage B(T+2)@P3
//   A_LOW/A_HIGH halves read through P3        -> stage A(T+2)@P4
// vmcnt(3) before end-P3 barrier: only B(T+2) in flight => tile T+1 landed
// before P4 read-ahead. Tail (T >= nt-2): vmcnt(0).
// Optional fused kv-copy epilogue (kvdst != nullptr): each block copies
// kvchunk float4s starting at blockIdx.x*kvchunk.
// ---------------------------------------------------------------------------
template <int OUT_BF16>
__global__ __launch_bounds__(512, 2)
void gemm5(const ushort* __restrict__ A, const ushort* __restrict__ B,
           void* __restrict__ Cv, int M, int N, int K, float scale,
           const float4* __restrict__ kvsrc, float4* __restrict__ kvdst,
           int kvchunk) {
  __shared__ __align__(16) char smem[114688];

  const int t    = threadIdx.x;
  const int w    = t >> 6;
  const int lane = t & 63;
  const int wr   = w >> 2;             // 0..1  (M: 128 rows each)
  const int wc   = w & 3;              // 0..3  (N: 48 cols each)
  const int fr   = lane & 15;
  const int g    = lane >> 4;          // 0..3

  // XCD-aware bijective swizzle: nwg % 8 == 0 by construction.
  const int nwg = gridDim.x;
  const int cpx = nwg >> 3;
  const int wg  = (blockIdx.x & 7) * cpx + (blockIdx.x >> 3);
  const int nbx = N / 192;
  const int bx  = wg % nbx, by = wg / nbx;
  const int rowBase = by * 256, colBase = bx * 192;

  // Staging: pass covers 64 rows; wave w rows [w*8, w*8+8); lane l row +l>>3,
  // stored chunk l&7 holds logical chunk (l&7)^(l>>3)  (row&7 == l>>3).
  const int sr   = lane >> 3;                       // 0..7
  const int scol = ((lane & 7) ^ sr) << 3;          // pre-swizzled source col
  const ushort* Ag = A + (size_t)(rowBase + w * 8 + sr) * K + scol;
  const ushort* Bg = B + (size_t)(colBase + w * 8 + sr) * K + scol;
  const int wofs = w * 1024;                        // wave LDS byte offset

#define STAGE_A_LOW(kt)  do { char* d_ = smem + ((kt) & 1) * 57344 + wofs;          \
    const ushort* s_ = Ag + (size_t)(kt) * 64;                                      \
    gload16(s_, d_); gload16(s_ + (size_t)64 * K, d_ + 8192); } while (0)
#define STAGE_A_HIGH(kt) do { char* d_ = smem + ((kt) & 1) * 57344 + 16384 + wofs;  \
    const ushort* s_ = Ag + (size_t)128 * K + (size_t)(kt) * 64;                    \
    gload16(s_, d_); gload16(s_ + (size_t)64 * K, d_ + 8192); } while (0)
#define STAGE_B(kt)      do { char* d_ = smem + ((kt) & 1) * 57344 + 32768 + wofs;  \
    const ushort* s_ = Bg + (size_t)(kt) * 64;                                      \
    gload16(s_, d_); gload16(s_ + (size_t)64 * K, d_ + 8192);                       \
    gload16(s_ + (size_t)128 * K, d_ + 16384); } while (0)

  // Fragment read geometry (byte offsets). Row stride 128B; logical chunk
  // kh*4+g stored at (kh*4+g)^(fr&7) since row&7 == fr&7 for all frag rows.
  const int aBase = (wr * 128 + fr) * 128;
  const int bBase = 32768 + (wc * 48 + fr) * 128;
  const int cs0   = (g ^ (fr & 7)) << 4;            // kh=0
  const int cs1   = ((4 | g) ^ (fr & 7)) << 4;      // kh=1

#define READ_A(dst, bo, MH, CS) do {                                  \
    const char* p_ = smem + (bo) + aBase + (MH) * 8192 + (CS);        \
    dst[0] = *(const bf16x8*)(p_);                                    \
    dst[1] = *(const bf16x8*)(p_ + 2048);                             \
    dst[2] = *(const bf16x8*)(p_ + 4096);                             \
    dst[3] = *(const bf16x8*)(p_ + 6144); } while (0)
#define READ_B(dst, bo, CS) do {                                      \
    const char* p_ = smem + (bo) + bBase + (CS);                      \
    dst[0] = *(const bf16x8*)(p_);                                    \
    dst[1] = *(const bf16x8*)(p_ + 2048);                             \
    dst[2] = *(const bf16x8*)(p_ + 4096); } while (0)
#define MFMA_Q(MH, aset, bset) do {                                   \
    _Pragma("unroll") for (int mi_ = 0; mi_ < 4; ++mi_)               \
    _Pragma("unroll") for (int ni_ = 0; ni_ < 3; ++ni_)               \
      acc[(MH) * 4 + mi_][ni_] = __builtin_amdgcn_mfma_f32_16x16x32_bf16( \
          aset[mi_], bset[ni_], acc[(MH) * 4 + mi_][ni_], 0, 0, 0); } while (0)

  f32x4 acc[8][3];
#pragma unroll
  for (int m = 0; m < 8; ++m)
#pragma unroll
    for (int n = 0; n < 3; ++n)
      acc[m][n] = f32x4{0.f, 0.f, 0.f, 0.f};

  bf16x8 aA[4], aB[4], Bk0[3], Bk1[3];

  const int nt = K >> 6;               // 48

  // Prologue: stage tiles 0,1 fully; wait tile 0; pre-read q(0,0) regs.
  STAGE_A_LOW(0); STAGE_B(0); STAGE_A_HIGH(0);
  STAGE_A_LOW(1); STAGE_B(1); STAGE_A_HIGH(1);
  VM(7);
  BAR;
  READ_A(aA, 0, 0, cs0);
  READ_B(Bk0, 0, cs0);

  for (int T = 0; T < nt; ++T) {
    const int bo  = (T & 1) * 57344;
    const int bon = 57344 - bo;
    const bool stg = (T + 2) < nt;
    // ---- P1: compute q(mh0,kh0); read-ahead A(mh0,kh1), B(kh1)
    READ_A(aB, bo, 0, cs1);
    READ_B(Bk1, bo, cs1);
    BAR; LGKM0;
    __builtin_amdgcn_s_setprio(1); MFMA_Q(0, aA, Bk0); __builtin_amdgcn_s_setprio(0);
    BAR;
    // ---- P2: compute q(mh0,kh1); read-ahead A(mh1,kh0)
    READ_A(aA, bo, 1, cs0);
    BAR; LGKM0;
    __builtin_amdgcn_s_setprio(1); MFMA_Q(0, aB, Bk1); __builtin_amdgcn_s_setprio(0);
    BAR;
    // ---- P3: stage B(T+2); compute q(mh1,kh0); read-ahead A(mh1,kh1)
    if (stg) STAGE_B(T + 2);
    READ_A(aB, bo, 1, cs1);
    BAR; LGKM0;
    __builtin_amdgcn_s_setprio(1); MFMA_Q(1, aA, Bk0); __builtin_amdgcn_s_setprio(0);
    if (T < nt - 2) { VM(3); } else { VM(0); }   // tile T+1 fully landed
    BAR;
    // ---- P4: stage A_LOW+A_HIGH(T+2); compute q(mh1,kh1); read next tile
    if (stg) { STAGE_A_LOW(T + 2); STAGE_A_HIGH(T + 2); }
    if (T + 1 < nt) { READ_A(aA, bon, 0, cs0); READ_B(Bk0, bon, cs0); }
    BAR; LGKM0;
    __builtin_amdgcn_s_setprio(1); MFMA_Q(1, aB, Bk1); __builtin_amdgcn_s_setprio(0);
    BAR;
  }

#undef STAGE_A_LOW
#undef STAGE_A_HIGH
#undef STAGE_B
#undef READ_A
#undef READ_B
#undef MFMA_Q

  // C/D layout: col = lane&15, row = (lane>>4)*4 + i
  const int orow = rowBase + wr * 128 + (g << 2);
  const int ocol = colBase + wc * 48 + fr;
#pragma unroll
  for (int mi = 0; mi < 8; ++mi)
#pragma unroll
    for (int ni = 0; ni < 3; ++ni)
#pragma unroll
      for (int i = 0; i < 4; ++i) {
        const size_t idx = (size_t)(orow + mi * 16 + i) * N + (ocol + ni * 16);
        float v = acc[mi][ni][i] * scale;
        if (OUT_BF16) ((ushort*)Cv)[idx] = f2bf(v);
        else          ((float*)Cv)[idx]  = v;
      }

  // Fused kv_cache passthrough: block b copies float4s
  // [b*kvchunk, (b+1)*kvchunk). Coalesced, rides under other blocks' MFMA.
  if (kvdst) {
    size_t beg = (size_t)blockIdx.x * kvchunk;
    for (int i = t; i < kvchunk; i += 512)
      kvdst[beg + i] = kvsrc[beg + i];
  }
}

extern "C" void kernel_launch(void* const* d_in, const int* in_sizes, int n_in,
                              void* d_out, int out_size, void* d_ws, size_t ws_size,
                              hipStream_t stream) {
  const float* hs = (const float*)d_in[0];   // (4,2048,3072)
  const float* kv = (const float*)d_in[4];   // (4,2,8,4096,128)
  const float* Wq = (const float*)d_in[5];   // (3072,3072) (d,h)
  const float* Wo = (const float*)d_in[8];   // (3072,3072) (o,d)

  const int M = 8192, H = 3072;
  const int OUT_ELEMS = M * H;
  const int nkv  = in_sizes[4];              // 33_554_432 floats
  const int nkv4 = nkv / 4;                  // 8_388_608 float4
  const int kvchunk = nkv4 / 512;            // 16384 (exact)

  float* out = (float*)d_out;

  // Workspace (bf16): Xb 48MB, Wob 18MB, WqTb 18MB, [Wb 18MB if it fits].
  ushort* Xb   = (ushort*)d_ws;
  ushort* Wob  = Xb + (size_t)M * H;
  ushort* WqTb = Wob + (size_t)H * H;
  const size_t WS_NEED = 2ull * ((size_t)M * H + 3ull * (size_t)H * H);
  const bool ws_ok = ws_size >= WS_NEED;
  // Wb in ws when possible (enables fused kv copy); else in d_out kv-tail
  // (then the fused copy must be disabled: it would overwrite Wb mid-GEMM).
  ushort* Wb = ws_ok ? (WqTb + (size_t)H * H) : (ushort*)(out + OUT_ELEMS);

  cast_f32_to_bf16<<<2048, 256, 0, stream>>>((const float4*)hs, (ushort4*)Xb, (M * H) / 4);
  cast_f32_to_bf16<<<1024, 256, 0, stream>>>((const float4*)Wo, (ushort4*)Wob, (H * H) / 4);
  transpose_cast<<<dim3(H / 32, H / 32), 256, 0, stream>>>(Wq, WqTb, H, H);

  const float qk_scale = 0.08838834764831845f;  // 128^-0.5

  // Small GEMM: W[o,h] = s * sum_d Wo[o,d]*Wq[d,h]; grid 12*16 = 192 (%8==0).
  gemm5<1><<<(H / 256) * (H / 192), 512, 0, stream>>>(
      Wob, WqTb, (void*)Wb, H, H, H, qk_scale, nullptr, nullptr, 0);

  // Big GEMM: out[m,o] = sum_h X[m,h]*W[o,h]; grid 32*16 = 512 (%8==0);
  // fused kv copy (512 * 16384 float4 = the whole kv_cache).
  const float4* kvs = ws_ok ? (const float4*)kv : nullptr;
  float4* kvd = ws_ok ? (float4*)(out + OUT_ELEMS) : nullptr;
  gemm5<0><<<(M / 256) * (H / 192), 512, 0, stream>>>(
      Xb, Wb, (void*)out, M, H, H, 1.0f, kvs, kvd, kvchunk);

  if (!ws_ok) {
    hipMemcpyAsync(out + OUT_ELEMS, kv, (size_t)nkv * sizeof(float),
                   hipMemcpyDeviceToDevice, stream);
  }
}